// Round 9
// baseline (661.330 us; speedup 1.0000x reference)
//
#include <hip/hip_runtime.h>
#include <hip/hip_fp16.h>

#define B_  16
#define TA  2048
#define TV  1024
#define DD  512
#define NIT 20

static constexpr float EPSI  = 0.15f;
static constexpr float LOG2E = 1.4426950408889634f;

using f32x4 = __attribute__((ext_vector_type(4))) float;
using half8 = __attribute__((ext_vector_type(8))) _Float16;
using half4 = __attribute__((ext_vector_type(4))) _Float16;

__device__ inline float wave_sum(float x) {
  #pragma unroll
  for (int m = 32; m; m >>= 1) x += __shfl_xor(x, m, 64);
  return x;
}

// bank-spread swizzle for stride-64B f32 vector access (proven r4-r8)
__device__ inline int swz(int c) { return c ^ (((c >> 5) & 7) << 2); }

// ---------------- norms + normalized-f16 prepack ---------------------------
__global__ __launch_bounds__(256) void norms2_k(const float* __restrict__ audio,
                                                const float* __restrict__ video,
                                                _Float16* __restrict__ af16,
                                                _Float16* __restrict__ vf16) {
  int wid  = (blockIdx.x * blockDim.x + threadIdx.x) >> 6;
  int lane = threadIdx.x & 63;
  const float* src; _Float16* dst;
  if (wid < B_ * TA) {
    src = audio + (size_t)wid * DD; dst = af16 + (size_t)wid * DD;
  } else {
    int w2 = wid - B_ * TA;
    src = video + (size_t)w2 * DD; dst = vf16 + (size_t)w2 * DD;
  }
  float4 v0 = ((const float4*)src)[lane];
  float4 v1 = ((const float4*)src)[lane + 64];
  float ss = v0.x*v0.x + v0.y*v0.y + v0.z*v0.z + v0.w*v0.w
           + v1.x*v1.x + v1.y*v1.y + v1.z*v1.z + v1.w*v1.w;
  ss = wave_sum(ss);
  float sc = 1.0f / fmaxf(sqrtf(ss), 1e-12f);
  half4 h0 = { (_Float16)(v0.x * sc), (_Float16)(v0.y * sc),
               (_Float16)(v0.z * sc), (_Float16)(v0.w * sc) };
  half4 h1 = { (_Float16)(v1.x * sc), (_Float16)(v1.y * sc),
               (_Float16)(v1.z * sc), (_Float16)(v1.w * sc) };
  ((half4*)dst)[lane]      = h0;
  ((half4*)dst)[lane + 64] = h1;
}

// ---------------- plain norms (fallback paths) -----------------------------
__global__ __launch_bounds__(256) void norms_k(const float* __restrict__ audio,
                                               const float* __restrict__ video,
                                               float* __restrict__ inv_na,
                                               float* __restrict__ inv_nv) {
  int wid  = (blockIdx.x * blockDim.x + threadIdx.x) >> 6;
  int lane = threadIdx.x & 63;
  const float* src; float* dst;
  if (wid < B_ * TA) { src = audio + (size_t)wid * DD; dst = inv_na + wid; }
  else               { src = video + (size_t)(wid - B_ * TA) * DD; dst = inv_nv + (wid - B_ * TA); }
  const float4* s4 = (const float4*)src;
  float ss = 0.f;
  #pragma unroll
  for (int i = 0; i < 2; i++) {
    float4 v = s4[lane + i * 64];
    ss += v.x * v.x + v.y * v.y + v.z * v.z + v.w * v.w;
  }
  ss = wave_sum(ss);
  if (lane == 0) *dst = 1.0f / fmaxf(sqrtf(ss), 1e-12f);
}

// ---------------- v' init: v' = -c1 * lam_q * (1 - quality) ----------------
__global__ void vinit_k(const float* __restrict__ quality,
                        const float* __restrict__ lam_q,
                        float* __restrict__ Vp) {
  int i = blockIdx.x * blockDim.x + threadIdx.x;
  float c1 = LOG2E / EPSI;
  Vp[i] = -c1 * (*lam_q) * (1.0f - quality[i]);
}

#define BM 128
#define BN 128
#define BK 64
#define LDH 72

// ---------------- cost GEMM from pre-normalized f16, XCD-swizzled ----------
__global__ __launch_bounds__(256) void cost2_k(const _Float16* __restrict__ af16,
                                               const _Float16* __restrict__ vf16,
                                               const float* __restrict__ lam_t,
                                               _Float16* __restrict__ Kh) {
  __shared__ _Float16 As[BM * LDH];
  __shared__ _Float16 Bs[BN * LDH];
  int lin = blockIdx.x;                       // 2048 blocks
  int sw  = (lin & 7) * 256 + (lin >> 3);     // XCD gets contiguous work chunk
  int b   = sw >> 7;
  int rem = sw & 127;
  int j0  = (rem >> 4) * BN;
  int a0  = (rem & 15) * BM;
  int tid  = threadIdx.x;
  int lane = tid & 63;
  int wid  = tid >> 6;
  int wm = wid >> 1, wn = wid & 1;

  const _Float16* Ab = af16 + (size_t)b * TA * DD;
  const _Float16* Vb = vf16 + (size_t)b * TV * DD;

  f32x4 acc[4][4];
  #pragma unroll
  for (int i = 0; i < 4; i++)
    #pragma unroll
    for (int j = 0; j < 4; j++)
      #pragma unroll
      for (int r = 0; r < 4; r++) acc[i][j][r] = 0.f;

  int srow = tid >> 3;          // 0..31
  int sc8  = (tid & 7) * 8;     // half idx 0..56
  int l16 = lane & 15, lq = lane >> 4;

  for (int kb = 0; kb < DD; kb += BK) {
    __syncthreads();
    #pragma unroll
    for (int s = 0; s < 4; s++) {
      int r = srow + s * 32;
      *(half8*)&As[r * LDH + sc8] = *(const half8*)&Ab[(size_t)(a0 + r) * DD + kb + sc8];
      *(half8*)&Bs[r * LDH + sc8] = *(const half8*)&Vb[(size_t)(j0 + r) * DD + kb + sc8];
    }
    __syncthreads();
    #pragma unroll
    for (int ks = 0; ks < 2; ks++) {
      half8 af[4], bf[4];
      #pragma unroll
      for (int mf = 0; mf < 4; mf++)
        af[mf] = *(const half8*)&As[(wm * 64 + mf * 16 + l16) * LDH + ks * 32 + lq * 8];
      #pragma unroll
      for (int nf = 0; nf < 4; nf++)
        bf[nf] = *(const half8*)&Bs[(wn * 64 + nf * 16 + l16) * LDH + ks * 32 + lq * 8];
      #pragma unroll
      for (int mf = 0; mf < 4; mf++)
        #pragma unroll
        for (int nf = 0; nf < 4; nf++)
          acc[mf][nf] = __builtin_amdgcn_mfma_f32_16x16x32_f16(af[mf], bf[nf], acc[mf][nf], 0, 0, 0);
    }
  }

  float lt = *lam_t;
  float c1 = LOG2E / EPSI;
  #pragma unroll
  for (int mf = 0; mf < 4; mf++)
    #pragma unroll
    for (int nf = 0; nf < 4; nf++)
      #pragma unroll
      for (int r = 0; r < 4; r++) {
        int a = a0 + wm * 64 + mf * 16 + lq * 4 + r;
        int j = j0 + wn * 64 + nf * 16 + l16;
        float sim = acc[mf][nf][r];
        float td = fabsf((float)a * (1.0f / TA) - (float)j * (1.0f / TV));
        Kh[((size_t)b * TA + a) * TV + j] = (_Float16)(c1 * (sim - 1.0f - lt * td));
      }
}

// ---------------- fused Sinkhorn step: combine + scan (+ final write) ------
// 256 blocks x 512 thr (8 waves); wave = 16 rows; block = 128 rows;
// 16 blocks/batch -> combine reads only 16 chunks (16 MB/iter total).
// MODE 0: first scan.  MODE 1: combine prev partials, persist Vp (one block
// per batch), emit new partials.  MODE 2: combine and write final transport.
template<int MODE>
__global__ __launch_bounds__(512) void step_k(const _Float16* __restrict__ Kh,
                                              const float* __restrict__ Vp_in,
                                              float* __restrict__ Vp_out,
                                              const float* __restrict__ pc_in,
                                              float* __restrict__ pc_out,
                                              float* __restrict__ out) {
  __shared__ float lc[8][1024];
  __shared__ float vbuf[1024];
  const int tid = threadIdx.x, lane = tid & 63, wid = tid >> 6;
  const int bid  = blockIdx.x;             // 0..255
  const int row0 = bid * 128 + wid * 16;   // wave's first global row
  const int b    = bid >> 4;               // batch

  // phase A: reconstruct this batch's current Vp into vbuf
  if (MODE == 0) {
    #pragma unroll
    for (int k = 0; k < 2; k++) {
      int col = tid + k * 512;
      vbuf[swz(col)] = Vp_in[b * TV + col];
    }
  } else {
    #pragma unroll
    for (int k = 0; k < 2; k++) {
      int col = tid + k * 512;
      const float* p = pc_in + ((size_t)b * 16) * 1024 + col;
      float S = 0.f;
      #pragma unroll
      for (int c = 0; c < 16; c++) S += p[c * 1024];
      float nv = Vp_in[b * TV + col] - log2f(S);
      vbuf[swz(col)] = nv;
      if (MODE == 1 && (bid & 15) == 0) Vp_out[b * TV + col] = nv;
    }
  }
  __syncthreads();

  float vpl[16];
  *(f32x4*)&vpl[0]  = *(const f32x4*)&vbuf[swz(lane * 8)];
  *(f32x4*)&vpl[4]  = *(const f32x4*)&vbuf[swz(lane * 8 + 4)];
  *(f32x4*)&vpl[8]  = *(const f32x4*)&vbuf[swz(512 + lane * 8)];
  *(f32x4*)&vpl[12] = *(const f32x4*)&vbuf[swz(512 + lane * 8 + 4)];

  float C[16];
  #pragma unroll
  for (int i = 0; i < 16; i++) C[i] = 0.f;

  #pragma unroll
  for (int pr = 0; pr < 8; pr++) {          // 16 rows in pairs for ILP
    const _Float16* rp0 = Kh + (size_t)(row0 + pr * 2) * TV + lane * 8;
    const _Float16* rp1 = Kh + (size_t)(row0 + pr * 2 + 1) * TV + lane * 8;
    half8 a0 = *(const half8*)&rp0[0];
    half8 a1 = *(const half8*)&rp0[512];
    half8 b0 = *(const half8*)&rp1[0];
    half8 b1 = *(const half8*)&rp1[512];
    float e0[16], e1[16];
    float s0 = 0.f, s1 = 0.f;
    #pragma unroll
    for (int i = 0; i < 8; i++) {
      e0[i] = exp2f((float)a0[i] + vpl[i]);     s0 += e0[i];
      e1[i] = exp2f((float)b0[i] + vpl[i]);     s1 += e1[i];
    }
    #pragma unroll
    for (int i = 0; i < 8; i++) {
      e0[8+i] = exp2f((float)a1[i] + vpl[8+i]); s0 += e0[8+i];
      e1[8+i] = exp2f((float)b1[i] + vpl[8+i]); s1 += e1[8+i];
    }
    #pragma unroll
    for (int m = 32; m; m >>= 1) {            // two interleaved reduce chains
      s0 += __shfl_xor(s0, m, 64);
      s1 += __shfl_xor(s1, m, 64);
    }
    float w0 = 1.0f / s0, w1 = 1.0f / s1;
    if (MODE == 2) {
      float* o0 = out + (size_t)(row0 + pr * 2) * TV + lane * 8;
      float* o1 = out + (size_t)(row0 + pr * 2 + 1) * TV + lane * 8;
      f32x4 t;
      t = (f32x4){e0[0]*w0, e0[1]*w0, e0[2]*w0, e0[3]*w0};     *(f32x4*)&o0[0]   = t;
      t = (f32x4){e0[4]*w0, e0[5]*w0, e0[6]*w0, e0[7]*w0};     *(f32x4*)&o0[4]   = t;
      t = (f32x4){e0[8]*w0, e0[9]*w0, e0[10]*w0, e0[11]*w0};   *(f32x4*)&o0[512] = t;
      t = (f32x4){e0[12]*w0, e0[13]*w0, e0[14]*w0, e0[15]*w0}; *(f32x4*)&o0[516] = t;
      t = (f32x4){e1[0]*w1, e1[1]*w1, e1[2]*w1, e1[3]*w1};     *(f32x4*)&o1[0]   = t;
      t = (f32x4){e1[4]*w1, e1[5]*w1, e1[6]*w1, e1[7]*w1};     *(f32x4*)&o1[4]   = t;
      t = (f32x4){e1[8]*w1, e1[9]*w1, e1[10]*w1, e1[11]*w1};   *(f32x4*)&o1[512] = t;
      t = (f32x4){e1[12]*w1, e1[13]*w1, e1[14]*w1, e1[15]*w1}; *(f32x4*)&o1[516] = t;
    } else {
      #pragma unroll
      for (int i = 0; i < 16; i++)
        C[i] = fmaf(e0[i], w0, fmaf(e1[i], w1, C[i]));
    }
  }

  if (MODE != 2) {
    *(f32x4*)&lc[wid][swz(lane * 8)]           = *(f32x4*)&C[0];
    *(f32x4*)&lc[wid][swz(lane * 8 + 4)]       = *(f32x4*)&C[4];
    *(f32x4*)&lc[wid][swz(512 + lane * 8)]     = *(f32x4*)&C[8];
    *(f32x4*)&lc[wid][swz(512 + lane * 8 + 4)] = *(f32x4*)&C[12];
    __syncthreads();
    #pragma unroll
    for (int k = 0; k < 2; k++) {
      int col = tid + k * 512;
      int sc_ = swz(col);
      float S = 0.f;
      #pragma unroll
      for (int w = 0; w < 8; w++) S += lc[w][sc_];
      pc_out[(size_t)bid * 1024 + col] = S;
    }
  }
}

// ---------------- r3 fallback kernels --------------------------------------
template<bool F16>
__global__ __launch_bounds__(256) void cost_k(const float* __restrict__ audio,
                                              const float* __restrict__ video,
                                              const float* __restrict__ inv_na,
                                              const float* __restrict__ inv_nv,
                                              const float* __restrict__ lam_t,
                                              float* __restrict__ Kb,
                                              _Float16* __restrict__ Kh) {
  __shared__ _Float16 As[BM * LDH];
  __shared__ _Float16 Bs[BN * LDH];
  int b  = blockIdx.z;
  int a0 = blockIdx.x * BM;
  int j0 = blockIdx.y * BN;
  int tid  = threadIdx.x;
  int lane = tid & 63;
  int wid  = tid >> 6;
  int wm = wid >> 1, wn = wid & 1;
  const float* Ab = audio + (size_t)b * TA * DD;
  const float* Vb = video + (size_t)b * TV * DD;
  f32x4 acc[4][4];
  #pragma unroll
  for (int i = 0; i < 4; i++)
    #pragma unroll
    for (int j = 0; j < 4; j++)
      #pragma unroll
      for (int r = 0; r < 4; r++) acc[i][j][r] = 0.f;
  int frow = tid >> 4;
  int fcol = (tid & 15) * 4;
  int l16 = lane & 15, lq = lane >> 4;
  for (int kb = 0; kb < DD; kb += BK) {
    __syncthreads();
    #pragma unroll
    for (int s = 0; s < 8; s++) {
      int r = frow + s * 16;
      float4 v = *(const float4*)&Ab[(size_t)(a0 + r) * DD + kb + fcol];
      float sc = inv_na[b * TA + a0 + r];
      half4 h = { (_Float16)(v.x * sc), (_Float16)(v.y * sc),
                  (_Float16)(v.z * sc), (_Float16)(v.w * sc) };
      *(half4*)&As[r * LDH + fcol] = h;
    }
    #pragma unroll
    for (int s = 0; s < 8; s++) {
      int r = frow + s * 16;
      float4 v = *(const float4*)&Vb[(size_t)(j0 + r) * DD + kb + fcol];
      float sc = inv_nv[b * TV + j0 + r];
      half4 h = { (_Float16)(v.x * sc), (_Float16)(v.y * sc),
                  (_Float16)(v.z * sc), (_Float16)(v.w * sc) };
      *(half4*)&Bs[r * LDH + fcol] = h;
    }
    __syncthreads();
    #pragma unroll
    for (int ks = 0; ks < 2; ks++) {
      half8 af[4], bf[4];
      #pragma unroll
      for (int mf = 0; mf < 4; mf++)
        af[mf] = *(const half8*)&As[(wm * 64 + mf * 16 + l16) * LDH + ks * 32 + lq * 8];
      #pragma unroll
      for (int nf = 0; nf < 4; nf++)
        bf[nf] = *(const half8*)&Bs[(wn * 64 + nf * 16 + l16) * LDH + ks * 32 + lq * 8];
      #pragma unroll
      for (int mf = 0; mf < 4; mf++)
        #pragma unroll
        for (int nf = 0; nf < 4; nf++)
          acc[mf][nf] = __builtin_amdgcn_mfma_f32_16x16x32_f16(af[mf], bf[nf], acc[mf][nf], 0, 0, 0);
    }
  }
  float lt = *lam_t;
  float c1 = LOG2E / EPSI;
  #pragma unroll
  for (int mf = 0; mf < 4; mf++)
    #pragma unroll
    for (int nf = 0; nf < 4; nf++)
      #pragma unroll
      for (int r = 0; r < 4; r++) {
        int a = a0 + wm * 64 + mf * 16 + lq * 4 + r;
        int j = j0 + wn * 64 + nf * 16 + l16;
        float sim = acc[mf][nf][r];
        float td = fabsf((float)a * (1.0f / TA) - (float)j * (1.0f / TV));
        float val = c1 * (sim - 1.0f - lt * td);
        size_t o = ((size_t)b * TA + a) * TV + j;
        if constexpr (F16) Kh[o] = (_Float16)val;
        else               Kb[o] = val;
      }
}

__global__ __launch_bounds__(512) void iter16_k(const _Float16* __restrict__ Kh,
                                                const float* __restrict__ Vp,
                                                float* __restrict__ pc) {
  __shared__ float lc[8][1024];
  int tid = threadIdx.x, lane = tid & 63, wid = tid >> 6;
  int row0 = (blockIdx.x * 8 + wid) * 8;
  int b = row0 >> 11;
  const float* vp = Vp + b * TV + lane * 8;
  float vpl[16];
  *(float4*)&vpl[0]  = *(const float4*)&vp[0];
  *(float4*)&vpl[4]  = *(const float4*)&vp[4];
  *(float4*)&vpl[8]  = *(const float4*)&vp[512];
  *(float4*)&vpl[12] = *(const float4*)&vp[516];
  float C[16];
  #pragma unroll
  for (int i = 0; i < 16; i++) C[i] = 0.f;
  #pragma unroll 2
  for (int r = 0; r < 8; r++) {
    const _Float16* row = Kh + (size_t)(row0 + r) * TV + lane * 8;
    half8 h0 = *(const half8*)&row[0];
    half8 h1 = *(const half8*)&row[512];
    float e[16];
    float s = 0.f;
    #pragma unroll
    for (int i = 0; i < 8; i++) { e[i] = exp2f((float)h0[i] + vpl[i]); s += e[i]; }
    #pragma unroll
    for (int i = 0; i < 8; i++) { e[8 + i] = exp2f((float)h1[i] + vpl[8 + i]); s += e[8 + i]; }
    s = wave_sum(s);
    float w = 1.0f / s;
    #pragma unroll
    for (int i = 0; i < 16; i++) C[i] = fmaf(e[i], w, C[i]);
  }
  *(float4*)&lc[wid][lane * 8]           = make_float4(C[0], C[1], C[2], C[3]);
  *(float4*)&lc[wid][lane * 8 + 4]       = make_float4(C[4], C[5], C[6], C[7]);
  *(float4*)&lc[wid][512 + lane * 8]     = make_float4(C[8], C[9], C[10], C[11]);
  *(float4*)&lc[wid][512 + lane * 8 + 4] = make_float4(C[12], C[13], C[14], C[15]);
  __syncthreads();
  #pragma unroll
  for (int k = 0; k < 2; k++) {
    int col = tid + k * 512;
    float S = 0.f;
    #pragma unroll
    for (int w = 0; w < 8; w++) S += lc[w][col];
    pc[(size_t)blockIdx.x * 1024 + col] = S;
  }
}

__global__ __launch_bounds__(512) void iter32_k(const float* __restrict__ Kb,
                                                const float* __restrict__ Vp,
                                                float* __restrict__ pc) {
  __shared__ float lc[8][1024];
  int tid = threadIdx.x, lane = tid & 63, wid = tid >> 6;
  int row0 = (blockIdx.x * 8 + wid) * 8;
  int b = row0 >> 11;
  const float* vp = Vp + b * TV;
  float vpl[16];
  #pragma unroll
  for (int q = 0; q < 4; q++)
    *(float4*)&vpl[q * 4] = *(const float4*)&vp[q * 256 + lane * 4];
  float C[16];
  #pragma unroll
  for (int i = 0; i < 16; i++) C[i] = 0.f;
  #pragma unroll 2
  for (int r = 0; r < 8; r++) {
    const float* row = Kb + (size_t)(row0 + r) * TV;
    float e[16];
    float s = 0.f;
    #pragma unroll
    for (int q = 0; q < 4; q++) {
      float4 kv = *(const float4*)&row[q * 256 + lane * 4];
      e[q*4+0] = exp2f(kv.x + vpl[q*4+0]);
      e[q*4+1] = exp2f(kv.y + vpl[q*4+1]);
      e[q*4+2] = exp2f(kv.z + vpl[q*4+2]);
      e[q*4+3] = exp2f(kv.w + vpl[q*4+3]);
      s += e[q*4+0] + e[q*4+1] + e[q*4+2] + e[q*4+3];
    }
    s = wave_sum(s);
    float w = 1.0f / s;
    #pragma unroll
    for (int i = 0; i < 16; i++) C[i] = fmaf(e[i], w, C[i]);
  }
  #pragma unroll
  for (int q = 0; q < 4; q++)
    *(float4*)&lc[wid][q * 256 + lane * 4] =
        make_float4(C[q*4+0], C[q*4+1], C[q*4+2], C[q*4+3]);
  __syncthreads();
  #pragma unroll
  for (int k = 0; k < 2; k++) {
    int col = tid + k * 512;
    float S = 0.f;
    #pragma unroll
    for (int w = 0; w < 8; w++) S += lc[w][col];
    pc[(size_t)blockIdx.x * 1024 + col] = S;
  }
}

__global__ void vcomb_k(const float* __restrict__ pc, float* __restrict__ Vp) {
  int i = blockIdx.x * blockDim.x + threadIdx.x;
  int b = i >> 10, j = i & 1023;
  const float* p = pc + (size_t)(b * 32) * 1024 + j;
  float S = 0.f;
  #pragma unroll
  for (int c = 0; c < 32; c++) S += p[c * 1024];
  Vp[i] -= log2f(S);
}

__global__ __launch_bounds__(256) void final16_k(const _Float16* __restrict__ Kh,
                                                 const float* __restrict__ Vp,
                                                 float* __restrict__ out) {
  int gw   = (blockIdx.x * blockDim.x + threadIdx.x) >> 6;
  int lane = threadIdx.x & 63;
  int b = gw >> 11;
  const float* vp = Vp + b * TV + lane * 8;
  float vpl[16];
  *(float4*)&vpl[0]  = *(const float4*)&vp[0];
  *(float4*)&vpl[4]  = *(const float4*)&vp[4];
  *(float4*)&vpl[8]  = *(const float4*)&vp[512];
  *(float4*)&vpl[12] = *(const float4*)&vp[516];
  const _Float16* row = Kh + (size_t)gw * TV + lane * 8;
  half8 h0 = *(const half8*)&row[0];
  half8 h1 = *(const half8*)&row[512];
  float e[16];
  float s = 0.f;
  #pragma unroll
  for (int i = 0; i < 8; i++) { e[i] = exp2f((float)h0[i] + vpl[i]); s += e[i]; }
  #pragma unroll
  for (int i = 0; i < 8; i++) { e[8 + i] = exp2f((float)h1[i] + vpl[8 + i]); s += e[8 + i]; }
  s = wave_sum(s);
  float inv = 1.0f / s;
  float* o = out + (size_t)gw * TV + lane * 8;
  *(float4*)&o[0]   = make_float4(e[0] * inv, e[1] * inv, e[2] * inv, e[3] * inv);
  *(float4*)&o[4]   = make_float4(e[4] * inv, e[5] * inv, e[6] * inv, e[7] * inv);
  *(float4*)&o[512] = make_float4(e[8] * inv, e[9] * inv, e[10] * inv, e[11] * inv);
  *(float4*)&o[516] = make_float4(e[12] * inv, e[13] * inv, e[14] * inv, e[15] * inv);
}

__global__ __launch_bounds__(256) void final32_k(float* __restrict__ Kb,
                                                 const float* __restrict__ Vp) {
  int gw   = (blockIdx.x * blockDim.x + threadIdx.x) >> 6;
  int lane = threadIdx.x & 63;
  int b = gw >> 11;
  const float* vp = Vp + b * TV;
  float* row = Kb + (size_t)gw * TV;
  float e[16];
  float s = 0.f;
  #pragma unroll
  for (int q = 0; q < 4; q++) {
    float4 kv = *(const float4*)&row[q * 256 + lane * 4];
    float4 vv = *(const float4*)&vp[q * 256 + lane * 4];
    e[q*4+0] = exp2f(kv.x + vv.x); e[q*4+1] = exp2f(kv.y + vv.y);
    e[q*4+2] = exp2f(kv.z + vv.z); e[q*4+3] = exp2f(kv.w + vv.w);
    s += e[q*4+0] + e[q*4+1] + e[q*4+2] + e[q*4+3];
  }
  s = wave_sum(s);
  float inv = 1.0f / s;
  #pragma unroll
  for (int q = 0; q < 4; q++)
    *(float4*)&row[q * 256 + lane * 4] =
        make_float4(e[q*4+0] * inv, e[q*4+1] * inv, e[q*4+2] * inv, e[q*4+3] * inv);
}

extern "C" void kernel_launch(void* const* d_in, const int* in_sizes, int n_in,
                              void* d_out, int out_size, void* d_ws, size_t ws_size,
                              hipStream_t stream) {
  const float* audio   = (const float*)d_in[0];
  const float* video   = (const float*)d_in[1];
  const float* quality = (const float*)d_in[2];
  const float* lam_t   = (const float*)d_in[3];
  const float* lam_q   = (const float*)d_in[4];

  float* out = (float*)d_out;
  float* ws  = (float*)d_ws;
  // full-path layout (f32 units)
  float* VpX    = ws + 49152;                      // 16384
  float* VpY    = ws + 65536;                      // 16384
  float* pcA    = ws + 81920;                      // 262144 (256*1024)
  float* pcB    = ws + 344064;                     // 262144
  _Float16* af16 = (_Float16*)(ws + 606208);       // 8388608 f32 slots (32 MiB)
  _Float16* vf16 = (_Float16*)(ws + 8994816);      // 4194304 f32 slots (16 MiB)
  _Float16* KhF  = (_Float16*)(ws + 13189120);     // 16777216 f32 slots (64 MiB)
  size_t need_full = 29966336ull * 4;

  // mid-path (r3) layout
  float* inv_na = ws;
  float* inv_nv = ws + 32768;
  float* VpM    = ws + 49152;
  float* pcM    = ws + 65536;
  _Float16* KhM = (_Float16*)(ws + 589824);
  size_t need_mid = (589824ull + 16777216ull) * 4;

  if (ws_size >= need_full) {
    norms2_k<<<12288, 256, 0, stream>>>(audio, video, af16, vf16);
    vinit_k<<<64, 256, 0, stream>>>(quality, lam_q, VpX);
    cost2_k<<<2048, 256, 0, stream>>>(af16, vf16, lam_t, KhF);

    step_k<0><<<256, 512, 0, stream>>>(KhF, VpX, nullptr, nullptr, pcA, nullptr);
    float* vin = VpX; float* vout = VpY;
    float* pin = pcA; float* pout = pcB;
    for (int t = 2; t <= NIT; t++) {
      step_k<1><<<256, 512, 0, stream>>>(KhF, vin, vout, pin, pout, nullptr);
      float* tmp = vin; vin = vout; vout = tmp;
      tmp = pin; pin = pout; pout = tmp;
    }
    step_k<2><<<256, 512, 0, stream>>>(KhF, vin, nullptr, pin, nullptr, out);
  } else if (ws_size >= need_mid) {
    norms_k<<<12288, 256, 0, stream>>>(audio, video, inv_na, inv_nv);
    vinit_k<<<64, 256, 0, stream>>>(quality, lam_q, VpM);
    cost_k<true><<<dim3(16, 8, 16), 256, 0, stream>>>(audio, video, inv_na, inv_nv,
                                                      lam_t, nullptr, KhM);
    for (int it = 0; it < NIT; it++) {
      iter16_k<<<512, 512, 0, stream>>>(KhM, VpM, pcM);
      vcomb_k<<<64, 256, 0, stream>>>(pcM, VpM);
    }
    final16_k<<<8192, 256, 0, stream>>>(KhM, VpM, out);
  } else {
    norms_k<<<12288, 256, 0, stream>>>(audio, video, inv_na, inv_nv);
    vinit_k<<<64, 256, 0, stream>>>(quality, lam_q, VpM);
    float* Kb = out;
    cost_k<false><<<dim3(16, 8, 16), 256, 0, stream>>>(audio, video, inv_na, inv_nv,
                                                       lam_t, Kb, nullptr);
    for (int it = 0; it < NIT; it++) {
      iter32_k<<<512, 512, 0, stream>>>(Kb, VpM, pcM);
      vcomb_k<<<64, 256, 0, stream>>>(pcM, VpM);
    }
    final32_k<<<8192, 256, 0, stream>>>(Kb, VpM);
  }
}

// Round 10
// 587.590 us; speedup vs baseline: 1.1255x; 1.1255x over previous
//
#include <hip/hip_runtime.h>
#include <hip/hip_fp16.h>

#define B_  16
#define TA  2048
#define TV  1024
#define DD  512
#define NIT 20

static constexpr float EPSI  = 0.15f;
static constexpr float LOG2E = 1.4426950408889634f;

using f32x4 = __attribute__((ext_vector_type(4))) float;
using half8 = __attribute__((ext_vector_type(8))) _Float16;
using half4 = __attribute__((ext_vector_type(4))) _Float16;

__device__ inline float wave_sum(float x) {
  #pragma unroll
  for (int m = 32; m; m >>= 1) x += __shfl_xor(x, m, 64);
  return x;
}

// ---------------- norms + normalized-f16 prepack ---------------------------
__global__ __launch_bounds__(256) void norms2_k(const float* __restrict__ audio,
                                                const float* __restrict__ video,
                                                _Float16* __restrict__ af16,
                                                _Float16* __restrict__ vf16) {
  int wid  = (blockIdx.x * blockDim.x + threadIdx.x) >> 6;
  int lane = threadIdx.x & 63;
  const float* src; _Float16* dst;
  if (wid < B_ * TA) {
    src = audio + (size_t)wid * DD; dst = af16 + (size_t)wid * DD;
  } else {
    int w2 = wid - B_ * TA;
    src = video + (size_t)w2 * DD; dst = vf16 + (size_t)w2 * DD;
  }
  float4 v0 = ((const float4*)src)[lane];
  float4 v1 = ((const float4*)src)[lane + 64];
  float ss = v0.x*v0.x + v0.y*v0.y + v0.z*v0.z + v0.w*v0.w
           + v1.x*v1.x + v1.y*v1.y + v1.z*v1.z + v1.w*v1.w;
  ss = wave_sum(ss);
  float sc = 1.0f / fmaxf(sqrtf(ss), 1e-12f);
  half4 h0 = { (_Float16)(v0.x * sc), (_Float16)(v0.y * sc),
               (_Float16)(v0.z * sc), (_Float16)(v0.w * sc) };
  half4 h1 = { (_Float16)(v1.x * sc), (_Float16)(v1.y * sc),
               (_Float16)(v1.z * sc), (_Float16)(v1.w * sc) };
  ((half4*)dst)[lane]      = h0;
  ((half4*)dst)[lane + 64] = h1;
}

// ---------------- plain norms (fallback paths) -----------------------------
__global__ __launch_bounds__(256) void norms_k(const float* __restrict__ audio,
                                               const float* __restrict__ video,
                                               float* __restrict__ inv_na,
                                               float* __restrict__ inv_nv) {
  int wid  = (blockIdx.x * blockDim.x + threadIdx.x) >> 6;
  int lane = threadIdx.x & 63;
  const float* src; float* dst;
  if (wid < B_ * TA) { src = audio + (size_t)wid * DD; dst = inv_na + wid; }
  else               { src = video + (size_t)(wid - B_ * TA) * DD; dst = inv_nv + (wid - B_ * TA); }
  const float4* s4 = (const float4*)src;
  float ss = 0.f;
  #pragma unroll
  for (int i = 0; i < 2; i++) {
    float4 v = s4[lane + i * 64];
    ss += v.x * v.x + v.y * v.y + v.z * v.z + v.w * v.w;
  }
  ss = wave_sum(ss);
  if (lane == 0) *dst = 1.0f / fmaxf(sqrtf(ss), 1e-12f);
}

// ---------------- v' init: v' = -c1 * lam_q * (1 - quality) ----------------
__global__ void vinit_k(const float* __restrict__ quality,
                        const float* __restrict__ lam_q,
                        float* __restrict__ Vp) {
  int i = blockIdx.x * blockDim.x + threadIdx.x;
  float c1 = LOG2E / EPSI;
  Vp[i] = -c1 * (*lam_q) * (1.0f - quality[i]);
}

#define BM 128
#define BN 128
#define BK 64
#define LDH 72

// ---------------- cost GEMM from pre-normalized f16, XCD-swizzled ----------
__global__ __launch_bounds__(256) void cost2_k(const _Float16* __restrict__ af16,
                                               const _Float16* __restrict__ vf16,
                                               const float* __restrict__ lam_t,
                                               _Float16* __restrict__ Kh) {
  __shared__ _Float16 As[BM * LDH];
  __shared__ _Float16 Bs[BN * LDH];
  int lin = blockIdx.x;                       // 2048 blocks
  int sw  = (lin & 7) * 256 + (lin >> 3);     // XCD gets contiguous work chunk
  int b   = sw >> 7;
  int rem = sw & 127;
  int j0  = (rem >> 4) * BN;
  int a0  = (rem & 15) * BM;
  int tid  = threadIdx.x;
  int lane = tid & 63;
  int wid  = tid >> 6;
  int wm = wid >> 1, wn = wid & 1;

  const _Float16* Ab = af16 + (size_t)b * TA * DD;
  const _Float16* Vb = vf16 + (size_t)b * TV * DD;

  f32x4 acc[4][4];
  #pragma unroll
  for (int i = 0; i < 4; i++)
    #pragma unroll
    for (int j = 0; j < 4; j++)
      #pragma unroll
      for (int r = 0; r < 4; r++) acc[i][j][r] = 0.f;

  int srow = tid >> 3;          // 0..31
  int sc8  = (tid & 7) * 8;     // half idx 0..56
  int l16 = lane & 15, lq = lane >> 4;

  for (int kb = 0; kb < DD; kb += BK) {
    __syncthreads();
    #pragma unroll
    for (int s = 0; s < 4; s++) {
      int r = srow + s * 32;
      *(half8*)&As[r * LDH + sc8] = *(const half8*)&Ab[(size_t)(a0 + r) * DD + kb + sc8];
      *(half8*)&Bs[r * LDH + sc8] = *(const half8*)&Vb[(size_t)(j0 + r) * DD + kb + sc8];
    }
    __syncthreads();
    #pragma unroll
    for (int ks = 0; ks < 2; ks++) {
      half8 af[4], bf[4];
      #pragma unroll
      for (int mf = 0; mf < 4; mf++)
        af[mf] = *(const half8*)&As[(wm * 64 + mf * 16 + l16) * LDH + ks * 32 + lq * 8];
      #pragma unroll
      for (int nf = 0; nf < 4; nf++)
        bf[nf] = *(const half8*)&Bs[(wn * 64 + nf * 16 + l16) * LDH + ks * 32 + lq * 8];
      #pragma unroll
      for (int mf = 0; mf < 4; mf++)
        #pragma unroll
        for (int nf = 0; nf < 4; nf++)
          acc[mf][nf] = __builtin_amdgcn_mfma_f32_16x16x32_f16(af[mf], bf[nf], acc[mf][nf], 0, 0, 0);
    }
  }

  float lt = *lam_t;
  float c1 = LOG2E / EPSI;
  #pragma unroll
  for (int mf = 0; mf < 4; mf++)
    #pragma unroll
    for (int nf = 0; nf < 4; nf++)
      #pragma unroll
      for (int r = 0; r < 4; r++) {
        int a = a0 + wm * 64 + mf * 16 + lq * 4 + r;
        int j = j0 + wn * 64 + nf * 16 + l16;
        float sim = acc[mf][nf][r];
        float td = fabsf((float)a * (1.0f / TA) - (float)j * (1.0f / TV));
        Kh[((size_t)b * TA + a) * TV + j] = (_Float16)(c1 * (sim - 1.0f - lt * td));
      }
}

// ---------------- iteration scan: upfront K loads for deep MLP -------------
// 512 blocks x 512 thr (8 waves); wave = 8 rows; 32 blocks/batch.
__global__ __launch_bounds__(512) void iterF_k(const _Float16* __restrict__ Kh,
                                               const float* __restrict__ Vp,
                                               float* __restrict__ pc) {
  __shared__ float lc[8][1024];
  int tid = threadIdx.x, lane = tid & 63, wid = tid >> 6;
  int row0 = (blockIdx.x * 8 + wid) * 8;
  int b = row0 >> 11;
  const float* vp = Vp + b * TV + lane * 8;
  float vpl[16];
  *(float4*)&vpl[0]  = *(const float4*)&vp[0];
  *(float4*)&vpl[4]  = *(const float4*)&vp[4];
  *(float4*)&vpl[8]  = *(const float4*)&vp[512];
  *(float4*)&vpl[12] = *(const float4*)&vp[516];

  // issue ALL 16 K loads before any compute (deep memory-level parallelism)
  half8 h[8][2];
  #pragma unroll
  for (int r = 0; r < 8; r++) {
    const _Float16* row = Kh + (size_t)(row0 + r) * TV + lane * 8;
    h[r][0] = *(const half8*)&row[0];
    h[r][1] = *(const half8*)&row[512];
  }

  float C[16];
  #pragma unroll
  for (int i = 0; i < 16; i++) C[i] = 0.f;

  #pragma unroll
  for (int pr = 0; pr < 4; pr++) {            // rows in pairs: 2 reduce chains
    float e0[16], e1[16];
    float s0 = 0.f, s1 = 0.f;
    #pragma unroll
    for (int i = 0; i < 8; i++) {
      e0[i]   = exp2f((float)h[2*pr+0][0][i] + vpl[i]);     s0 += e0[i];
      e1[i]   = exp2f((float)h[2*pr+1][0][i] + vpl[i]);     s1 += e1[i];
    }
    #pragma unroll
    for (int i = 0; i < 8; i++) {
      e0[8+i] = exp2f((float)h[2*pr+0][1][i] + vpl[8+i]);   s0 += e0[8+i];
      e1[8+i] = exp2f((float)h[2*pr+1][1][i] + vpl[8+i]);   s1 += e1[8+i];
    }
    #pragma unroll
    for (int m = 32; m; m >>= 1) {
      s0 += __shfl_xor(s0, m, 64);
      s1 += __shfl_xor(s1, m, 64);
    }
    float w0 = 1.0f / s0, w1 = 1.0f / s1;
    #pragma unroll
    for (int i = 0; i < 16; i++)
      C[i] = fmaf(e0[i], w0, fmaf(e1[i], w1, C[i]));
  }

  *(float4*)&lc[wid][lane * 8]           = make_float4(C[0], C[1], C[2], C[3]);
  *(float4*)&lc[wid][lane * 8 + 4]       = make_float4(C[4], C[5], C[6], C[7]);
  *(float4*)&lc[wid][512 + lane * 8]     = make_float4(C[8], C[9], C[10], C[11]);
  *(float4*)&lc[wid][512 + lane * 8 + 4] = make_float4(C[12], C[13], C[14], C[15]);
  __syncthreads();
  #pragma unroll
  for (int k = 0; k < 2; k++) {
    int col = tid + k * 512;
    float S = 0.f;
    #pragma unroll
    for (int w = 0; w < 8; w++) S += lc[w][col];
    pc[(size_t)blockIdx.x * 1024 + col] = S;
  }
}

// ---------------- v' update: Vp -= log2(sum of 32 partial colsums) ---------
__global__ void vcomb_k(const float* __restrict__ pc, float* __restrict__ Vp) {
  int i = blockIdx.x * blockDim.x + threadIdx.x;
  int b = i >> 10, j = i & 1023;
  const float* p = pc + (size_t)(b * 32) * 1024 + j;
  float S = 0.f;
  #pragma unroll
  for (int c = 0; c < 32; c++) S += p[c * 1024];
  Vp[i] -= log2f(S);
}

// ---------------- final: transport = row-softmax(K + v'_20) ----------------
__global__ __launch_bounds__(256) void final16_k(const _Float16* __restrict__ Kh,
                                                 const float* __restrict__ Vp,
                                                 float* __restrict__ out) {
  int gw   = (blockIdx.x * blockDim.x + threadIdx.x) >> 6;
  int lane = threadIdx.x & 63;
  int b = gw >> 11;
  const float* vp = Vp + b * TV + lane * 8;
  float vpl[16];
  *(float4*)&vpl[0]  = *(const float4*)&vp[0];
  *(float4*)&vpl[4]  = *(const float4*)&vp[4];
  *(float4*)&vpl[8]  = *(const float4*)&vp[512];
  *(float4*)&vpl[12] = *(const float4*)&vp[516];
  const _Float16* row = Kh + (size_t)gw * TV + lane * 8;
  half8 h0 = *(const half8*)&row[0];
  half8 h1 = *(const half8*)&row[512];
  float e[16];
  float s = 0.f;
  #pragma unroll
  for (int i = 0; i < 8; i++) { e[i] = exp2f((float)h0[i] + vpl[i]); s += e[i]; }
  #pragma unroll
  for (int i = 0; i < 8; i++) { e[8 + i] = exp2f((float)h1[i] + vpl[8 + i]); s += e[8 + i]; }
  s = wave_sum(s);
  float inv = 1.0f / s;
  float* o = out + (size_t)gw * TV + lane * 8;
  *(float4*)&o[0]   = make_float4(e[0] * inv, e[1] * inv, e[2] * inv, e[3] * inv);
  *(float4*)&o[4]   = make_float4(e[4] * inv, e[5] * inv, e[6] * inv, e[7] * inv);
  *(float4*)&o[512] = make_float4(e[8] * inv, e[9] * inv, e[10] * inv, e[11] * inv);
  *(float4*)&o[516] = make_float4(e[12] * inv, e[13] * inv, e[14] * inv, e[15] * inv);
}

// ---------------- fallback kernels (r3 mid path + f32 low path) ------------
template<bool F16>
__global__ __launch_bounds__(256) void cost_k(const float* __restrict__ audio,
                                              const float* __restrict__ video,
                                              const float* __restrict__ inv_na,
                                              const float* __restrict__ inv_nv,
                                              const float* __restrict__ lam_t,
                                              float* __restrict__ Kb,
                                              _Float16* __restrict__ Kh) {
  __shared__ _Float16 As[BM * LDH];
  __shared__ _Float16 Bs[BN * LDH];
  int b  = blockIdx.z;
  int a0 = blockIdx.x * BM;
  int j0 = blockIdx.y * BN;
  int tid  = threadIdx.x;
  int lane = tid & 63;
  int wid  = tid >> 6;
  int wm = wid >> 1, wn = wid & 1;
  const float* Ab = audio + (size_t)b * TA * DD;
  const float* Vb = video + (size_t)b * TV * DD;
  f32x4 acc[4][4];
  #pragma unroll
  for (int i = 0; i < 4; i++)
    #pragma unroll
    for (int j = 0; j < 4; j++)
      #pragma unroll
      for (int r = 0; r < 4; r++) acc[i][j][r] = 0.f;
  int frow = tid >> 4;
  int fcol = (tid & 15) * 4;
  int l16 = lane & 15, lq = lane >> 4;
  for (int kb = 0; kb < DD; kb += BK) {
    __syncthreads();
    #pragma unroll
    for (int s = 0; s < 8; s++) {
      int r = frow + s * 16;
      float4 v = *(const float4*)&Ab[(size_t)(a0 + r) * DD + kb + fcol];
      float sc = inv_na[b * TA + a0 + r];
      half4 h = { (_Float16)(v.x * sc), (_Float16)(v.y * sc),
                  (_Float16)(v.z * sc), (_Float16)(v.w * sc) };
      *(half4*)&As[r * LDH + fcol] = h;
    }
    #pragma unroll
    for (int s = 0; s < 8; s++) {
      int r = frow + s * 16;
      float4 v = *(const float4*)&Vb[(size_t)(j0 + r) * DD + kb + fcol];
      float sc = inv_nv[b * TV + j0 + r];
      half4 h = { (_Float16)(v.x * sc), (_Float16)(v.y * sc),
                  (_Float16)(v.z * sc), (_Float16)(v.w * sc) };
      *(half4*)&Bs[r * LDH + fcol] = h;
    }
    __syncthreads();
    #pragma unroll
    for (int ks = 0; ks < 2; ks++) {
      half8 af[4], bf[4];
      #pragma unroll
      for (int mf = 0; mf < 4; mf++)
        af[mf] = *(const half8*)&As[(wm * 64 + mf * 16 + l16) * LDH + ks * 32 + lq * 8];
      #pragma unroll
      for (int nf = 0; nf < 4; nf++)
        bf[nf] = *(const half8*)&Bs[(wn * 64 + nf * 16 + l16) * LDH + ks * 32 + lq * 8];
      #pragma unroll
      for (int mf = 0; mf < 4; mf++)
        #pragma unroll
        for (int nf = 0; nf < 4; nf++)
          acc[mf][nf] = __builtin_amdgcn_mfma_f32_16x16x32_f16(af[mf], bf[nf], acc[mf][nf], 0, 0, 0);
    }
  }
  float lt = *lam_t;
  float c1 = LOG2E / EPSI;
  #pragma unroll
  for (int mf = 0; mf < 4; mf++)
    #pragma unroll
    for (int nf = 0; nf < 4; nf++)
      #pragma unroll
      for (int r = 0; r < 4; r++) {
        int a = a0 + wm * 64 + mf * 16 + lq * 4 + r;
        int j = j0 + wn * 64 + nf * 16 + l16;
        float sim = acc[mf][nf][r];
        float td = fabsf((float)a * (1.0f / TA) - (float)j * (1.0f / TV));
        float val = c1 * (sim - 1.0f - lt * td);
        size_t o = ((size_t)b * TA + a) * TV + j;
        if constexpr (F16) Kh[o] = (_Float16)val;
        else               Kb[o] = val;
      }
}

__global__ __launch_bounds__(512) void iter32_k(const float* __restrict__ Kb,
                                                const float* __restrict__ Vp,
                                                float* __restrict__ pc) {
  __shared__ float lc[8][1024];
  int tid = threadIdx.x, lane = tid & 63, wid = tid >> 6;
  int row0 = (blockIdx.x * 8 + wid) * 8;
  int b = row0 >> 11;
  const float* vp = Vp + b * TV;
  float vpl[16];
  #pragma unroll
  for (int q = 0; q < 4; q++)
    *(float4*)&vpl[q * 4] = *(const float4*)&vp[q * 256 + lane * 4];
  float C[16];
  #pragma unroll
  for (int i = 0; i < 16; i++) C[i] = 0.f;
  #pragma unroll 2
  for (int r = 0; r < 8; r++) {
    const float* row = Kb + (size_t)(row0 + r) * TV;
    float e[16];
    float s = 0.f;
    #pragma unroll
    for (int q = 0; q < 4; q++) {
      float4 kv = *(const float4*)&row[q * 256 + lane * 4];
      e[q*4+0] = exp2f(kv.x + vpl[q*4+0]);
      e[q*4+1] = exp2f(kv.y + vpl[q*4+1]);
      e[q*4+2] = exp2f(kv.z + vpl[q*4+2]);
      e[q*4+3] = exp2f(kv.w + vpl[q*4+3]);
      s += e[q*4+0] + e[q*4+1] + e[q*4+2] + e[q*4+3];
    }
    s = wave_sum(s);
    float w = 1.0f / s;
    #pragma unroll
    for (int i = 0; i < 16; i++) C[i] = fmaf(e[i], w, C[i]);
  }
  #pragma unroll
  for (int q = 0; q < 4; q++)
    *(float4*)&lc[wid][q * 256 + lane * 4] =
        make_float4(C[q*4+0], C[q*4+1], C[q*4+2], C[q*4+3]);
  __syncthreads();
  #pragma unroll
  for (int k = 0; k < 2; k++) {
    int col = tid + k * 512;
    float S = 0.f;
    #pragma unroll
    for (int w = 0; w < 8; w++) S += lc[w][col];
    pc[(size_t)blockIdx.x * 1024 + col] = S;
  }
}

__global__ __launch_bounds__(256) void final32_k(float* __restrict__ Kb,
                                                 const float* __restrict__ Vp) {
  int gw   = (blockIdx.x * blockDim.x + threadIdx.x) >> 6;
  int lane = threadIdx.x & 63;
  int b = gw >> 11;
  const float* vp = Vp + b * TV;
  float* row = Kb + (size_t)gw * TV;
  float e[16];
  float s = 0.f;
  #pragma unroll
  for (int q = 0; q < 4; q++) {
    float4 kv = *(const float4*)&row[q * 256 + lane * 4];
    float4 vv = *(const float4*)&vp[q * 256 + lane * 4];
    e[q*4+0] = exp2f(kv.x + vv.x); e[q*4+1] = exp2f(kv.y + vv.y);
    e[q*4+2] = exp2f(kv.z + vv.z); e[q*4+3] = exp2f(kv.w + vv.w);
    s += e[q*4+0] + e[q*4+1] + e[q*4+2] + e[q*4+3];
  }
  s = wave_sum(s);
  float inv = 1.0f / s;
  #pragma unroll
  for (int q = 0; q < 4; q++)
    *(float4*)&row[q * 256 + lane * 4] =
        make_float4(e[q*4+0] * inv, e[q*4+1] * inv, e[q*4+2] * inv, e[q*4+3] * inv);
}

extern "C" void kernel_launch(void* const* d_in, const int* in_sizes, int n_in,
                              void* d_out, int out_size, void* d_ws, size_t ws_size,
                              hipStream_t stream) {
  const float* audio   = (const float*)d_in[0];
  const float* video   = (const float*)d_in[1];
  const float* quality = (const float*)d_in[2];
  const float* lam_t   = (const float*)d_in[3];
  const float* lam_q   = (const float*)d_in[4];

  float* out = (float*)d_out;
  float* ws  = (float*)d_ws;
  // full-path layout (f32 units)
  float* VpX    = ws + 49152;                      // 16384
  float* pc     = ws + 81920;                      // 524288 (512*1024)
  _Float16* af16 = (_Float16*)(ws + 606208);       // 32 MiB
  _Float16* vf16 = (_Float16*)(ws + 8994816);      // 16 MiB
  _Float16* KhF  = (_Float16*)(ws + 13189120);     // 64 MiB
  size_t need_full = 29966336ull * 4;

  // mid-path layout
  float* inv_na = ws;
  float* inv_nv = ws + 32768;
  float* VpM    = ws + 49152;
  float* pcM    = ws + 65536;
  _Float16* KhM = (_Float16*)(ws + 589824);
  size_t need_mid = (589824ull + 16777216ull) * 4;

  if (ws_size >= need_full) {
    norms2_k<<<12288, 256, 0, stream>>>(audio, video, af16, vf16);
    vinit_k<<<64, 256, 0, stream>>>(quality, lam_q, VpX);
    cost2_k<<<2048, 256, 0, stream>>>(af16, vf16, lam_t, KhF);
    for (int it = 0; it < NIT; it++) {
      iterF_k<<<512, 512, 0, stream>>>(KhF, VpX, pc);
      vcomb_k<<<64, 256, 0, stream>>>(pc, VpX);
    }
    final16_k<<<8192, 256, 0, stream>>>(KhF, VpX, out);
  } else if (ws_size >= need_mid) {
    norms_k<<<12288, 256, 0, stream>>>(audio, video, inv_na, inv_nv);
    vinit_k<<<64, 256, 0, stream>>>(quality, lam_q, VpM);
    cost_k<true><<<dim3(16, 8, 16), 256, 0, stream>>>(audio, video, inv_na, inv_nv,
                                                      lam_t, nullptr, KhM);
    for (int it = 0; it < NIT; it++) {
      iterF_k<<<512, 512, 0, stream>>>(KhM, VpM, pcM);
      vcomb_k<<<64, 256, 0, stream>>>(pcM, VpM);
    }
    final16_k<<<8192, 256, 0, stream>>>(KhM, VpM, out);
  } else {
    norms_k<<<12288, 256, 0, stream>>>(audio, video, inv_na, inv_nv);
    vinit_k<<<64, 256, 0, stream>>>(quality, lam_q, VpM);
    float* Kb = out;
    cost_k<false><<<dim3(16, 8, 16), 256, 0, stream>>>(audio, video, inv_na, inv_nv,
                                                       lam_t, Kb, nullptr);
    for (int it = 0; it < NIT; it++) {
      iter32_k<<<512, 512, 0, stream>>>(Kb, VpM, pcM);
      vcomb_k<<<64, 256, 0, stream>>>(pcM, VpM);
    }
    final32_k<<<8192, 256, 0, stream>>>(Kb, VpM);
  }
}

// Round 11
// 465.613 us; speedup vs baseline: 1.4203x; 1.2620x over previous
//
#include <hip/hip_runtime.h>
#include <hip/hip_fp16.h>

#define B_  16
#define TA  2048
#define TV  1024
#define DD  512
#define NIT 20

static constexpr float EPSI  = 0.15f;
static constexpr float LOG2E = 1.4426950408889634f;

using f32x4 = __attribute__((ext_vector_type(4))) float;
using half8 = __attribute__((ext_vector_type(8))) _Float16;
using half4 = __attribute__((ext_vector_type(4))) _Float16;

__device__ inline float wave_sum(float x) {
  #pragma unroll
  for (int m = 32; m; m >>= 1) x += __shfl_xor(x, m, 64);
  return x;
}

// ---------------- norms + normalized-f16 prepack ---------------------------
__global__ __launch_bounds__(256) void norms2_k(const float* __restrict__ audio,
                                                const float* __restrict__ video,
                                                _Float16* __restrict__ af16,
                                                _Float16* __restrict__ vf16) {
  int wid  = (blockIdx.x * blockDim.x + threadIdx.x) >> 6;
  int lane = threadIdx.x & 63;
  const float* src; _Float16* dst;
  if (wid < B_ * TA) {
    src = audio + (size_t)wid * DD; dst = af16 + (size_t)wid * DD;
  } else {
    int w2 = wid - B_ * TA;
    src = video + (size_t)w2 * DD; dst = vf16 + (size_t)w2 * DD;
  }
  float4 v0 = ((const float4*)src)[lane];
  float4 v1 = ((const float4*)src)[lane + 64];
  float ss = v0.x*v0.x + v0.y*v0.y + v0.z*v0.z + v0.w*v0.w
           + v1.x*v1.x + v1.y*v1.y + v1.z*v1.z + v1.w*v1.w;
  ss = wave_sum(ss);
  float sc = 1.0f / fmaxf(sqrtf(ss), 1e-12f);
  half4 h0 = { (_Float16)(v0.x * sc), (_Float16)(v0.y * sc),
               (_Float16)(v0.z * sc), (_Float16)(v0.w * sc) };
  half4 h1 = { (_Float16)(v1.x * sc), (_Float16)(v1.y * sc),
               (_Float16)(v1.z * sc), (_Float16)(v1.w * sc) };
  ((half4*)dst)[lane]      = h0;
  ((half4*)dst)[lane + 64] = h1;
}

// ---------------- plain norms (fallback paths) -----------------------------
__global__ __launch_bounds__(256) void norms_k(const float* __restrict__ audio,
                                               const float* __restrict__ video,
                                               float* __restrict__ inv_na,
                                               float* __restrict__ inv_nv) {
  int wid  = (blockIdx.x * blockDim.x + threadIdx.x) >> 6;
  int lane = threadIdx.x & 63;
  const float* src; float* dst;
  if (wid < B_ * TA) { src = audio + (size_t)wid * DD; dst = inv_na + wid; }
  else               { src = video + (size_t)(wid - B_ * TA) * DD; dst = inv_nv + (wid - B_ * TA); }
  const float4* s4 = (const float4*)src;
  float ss = 0.f;
  #pragma unroll
  for (int i = 0; i < 2; i++) {
    float4 v = s4[lane + i * 64];
    ss += v.x * v.x + v.y * v.y + v.z * v.z + v.w * v.w;
  }
  ss = wave_sum(ss);
  if (lane == 0) *dst = 1.0f / fmaxf(sqrtf(ss), 1e-12f);
}

// ---------------- v' init: v' = -c1 * lam_q * (1 - quality) ----------------
__global__ void vinit_k(const float* __restrict__ quality,
                        const float* __restrict__ lam_q,
                        float* __restrict__ Vp) {
  int i = blockIdx.x * blockDim.x + threadIdx.x;
  float c1 = LOG2E / EPSI;
  Vp[i] = -c1 * (*lam_q) * (1.0f - quality[i]);
}

#define BM 128
#define BN 128
#define BK 64
#define LDH 72

// ---------------- cost GEMM from pre-normalized f16, XCD-swizzled ----------
__global__ __launch_bounds__(256) void cost2_k(const _Float16* __restrict__ af16,
                                               const _Float16* __restrict__ vf16,
                                               const float* __restrict__ lam_t,
                                               _Float16* __restrict__ Kh) {
  __shared__ _Float16 As[BM * LDH];
  __shared__ _Float16 Bs[BN * LDH];
  int lin = blockIdx.x;                       // 2048 blocks
  int sw  = (lin & 7) * 256 + (lin >> 3);     // XCD gets contiguous work chunk
  int b   = sw >> 7;
  int rem = sw & 127;
  int j0  = (rem >> 4) * BN;
  int a0  = (rem & 15) * BM;
  int tid  = threadIdx.x;
  int lane = tid & 63;
  int wid  = tid >> 6;
  int wm = wid >> 1, wn = wid & 1;

  const _Float16* Ab = af16 + (size_t)b * TA * DD;
  const _Float16* Vb = vf16 + (size_t)b * TV * DD;

  f32x4 acc[4][4];
  #pragma unroll
  for (int i = 0; i < 4; i++)
    #pragma unroll
    for (int j = 0; j < 4; j++)
      #pragma unroll
      for (int r = 0; r < 4; r++) acc[i][j][r] = 0.f;

  int srow = tid >> 3;          // 0..31
  int sc8  = (tid & 7) * 8;     // half idx 0..56
  int l16 = lane & 15, lq = lane >> 4;

  for (int kb = 0; kb < DD; kb += BK) {
    __syncthreads();
    #pragma unroll
    for (int s = 0; s < 4; s++) {
      int r = srow + s * 32;
      *(half8*)&As[r * LDH + sc8] = *(const half8*)&Ab[(size_t)(a0 + r) * DD + kb + sc8];
      *(half8*)&Bs[r * LDH + sc8] = *(const half8*)&Vb[(size_t)(j0 + r) * DD + kb + sc8];
    }
    __syncthreads();
    #pragma unroll
    for (int ks = 0; ks < 2; ks++) {
      half8 af[4], bf[4];
      #pragma unroll
      for (int mf = 0; mf < 4; mf++)
        af[mf] = *(const half8*)&As[(wm * 64 + mf * 16 + l16) * LDH + ks * 32 + lq * 8];
      #pragma unroll
      for (int nf = 0; nf < 4; nf++)
        bf[nf] = *(const half8*)&Bs[(wn * 64 + nf * 16 + l16) * LDH + ks * 32 + lq * 8];
      #pragma unroll
      for (int mf = 0; mf < 4; mf++)
        #pragma unroll
        for (int nf = 0; nf < 4; nf++)
          acc[mf][nf] = __builtin_amdgcn_mfma_f32_16x16x32_f16(af[mf], bf[nf], acc[mf][nf], 0, 0, 0);
    }
  }

  float lt = *lam_t;
  float c1 = LOG2E / EPSI;
  #pragma unroll
  for (int mf = 0; mf < 4; mf++)
    #pragma unroll
    for (int nf = 0; nf < 4; nf++)
      #pragma unroll
      for (int r = 0; r < 4; r++) {
        int a = a0 + wm * 64 + mf * 16 + lq * 4 + r;
        int j = j0 + wn * 64 + nf * 16 + l16;
        float sim = acc[mf][nf][r];
        float td = fabsf((float)a * (1.0f / TA) - (float)j * (1.0f / TV));
        Kh[((size_t)b * TA + a) * TV + j] = (_Float16)(c1 * (sim - 1.0f - lt * td));
      }
}

// ---------------- iteration scan (r3-proven): 512 blocks x 8 waves ---------
__global__ __launch_bounds__(512) void iter16_k(const _Float16* __restrict__ Kh,
                                                const float* __restrict__ Vp,
                                                float* __restrict__ pc) {
  __shared__ float lc[8][1024];
  int tid = threadIdx.x, lane = tid & 63, wid = tid >> 6;
  int row0 = (blockIdx.x * 8 + wid) * 8;
  int b = row0 >> 11;
  const float* vp = Vp + b * TV + lane * 8;
  float vpl[16];
  *(float4*)&vpl[0]  = *(const float4*)&vp[0];
  *(float4*)&vpl[4]  = *(const float4*)&vp[4];
  *(float4*)&vpl[8]  = *(const float4*)&vp[512];
  *(float4*)&vpl[12] = *(const float4*)&vp[516];
  float C[16];
  #pragma unroll
  for (int i = 0; i < 16; i++) C[i] = 0.f;

  #pragma unroll 2
  for (int r = 0; r < 8; r++) {
    const _Float16* row = Kh + (size_t)(row0 + r) * TV + lane * 8;
    half8 h0 = *(const half8*)&row[0];
    half8 h1 = *(const half8*)&row[512];
    float e[16];
    float s = 0.f;
    #pragma unroll
    for (int i = 0; i < 8; i++) { e[i] = exp2f((float)h0[i] + vpl[i]); s += e[i]; }
    #pragma unroll
    for (int i = 0; i < 8; i++) { e[8 + i] = exp2f((float)h1[i] + vpl[8 + i]); s += e[8 + i]; }
    s = wave_sum(s);
    float w = 1.0f / s;
    #pragma unroll
    for (int i = 0; i < 16; i++) C[i] = fmaf(e[i], w, C[i]);
  }

  *(float4*)&lc[wid][lane * 8]           = make_float4(C[0], C[1], C[2], C[3]);
  *(float4*)&lc[wid][lane * 8 + 4]       = make_float4(C[4], C[5], C[6], C[7]);
  *(float4*)&lc[wid][512 + lane * 8]     = make_float4(C[8], C[9], C[10], C[11]);
  *(float4*)&lc[wid][512 + lane * 8 + 4] = make_float4(C[12], C[13], C[14], C[15]);
  __syncthreads();
  #pragma unroll
  for (int k = 0; k < 2; k++) {
    int col = tid + k * 512;
    float S = 0.f;
    #pragma unroll
    for (int w = 0; w < 8; w++) S += lc[w][col];
    pc[(size_t)blockIdx.x * 1024 + col] = S;
  }
}

// ---------------- v' update: Vp -= log2(sum of 32 partial colsums) ---------
__global__ void vcomb_k(const float* __restrict__ pc, float* __restrict__ Vp) {
  int i = blockIdx.x * blockDim.x + threadIdx.x;
  int b = i >> 10, j = i & 1023;
  const float* p = pc + (size_t)(b * 32) * 1024 + j;
  float S = 0.f;
  #pragma unroll
  for (int c = 0; c < 32; c++) S += p[c * 1024];
  Vp[i] -= log2f(S);
}

// ---------------- final: transport = row-softmax(K + v'_20) ----------------
__global__ __launch_bounds__(256) void final16_k(const _Float16* __restrict__ Kh,
                                                 const float* __restrict__ Vp,
                                                 float* __restrict__ out) {
  int gw   = (blockIdx.x * blockDim.x + threadIdx.x) >> 6;
  int lane = threadIdx.x & 63;
  int b = gw >> 11;
  const float* vp = Vp + b * TV + lane * 8;
  float vpl[16];
  *(float4*)&vpl[0]  = *(const float4*)&vp[0];
  *(float4*)&vpl[4]  = *(const float4*)&vp[4];
  *(float4*)&vpl[8]  = *(const float4*)&vp[512];
  *(float4*)&vpl[12] = *(const float4*)&vp[516];
  const _Float16* row = Kh + (size_t)gw * TV + lane * 8;
  half8 h0 = *(const half8*)&row[0];
  half8 h1 = *(const half8*)&row[512];
  float e[16];
  float s = 0.f;
  #pragma unroll
  for (int i = 0; i < 8; i++) { e[i] = exp2f((float)h0[i] + vpl[i]); s += e[i]; }
  #pragma unroll
  for (int i = 0; i < 8; i++) { e[8 + i] = exp2f((float)h1[i] + vpl[8 + i]); s += e[8 + i]; }
  s = wave_sum(s);
  float inv = 1.0f / s;
  float* o = out + (size_t)gw * TV + lane * 8;
  *(float4*)&o[0]   = make_float4(e[0] * inv, e[1] * inv, e[2] * inv, e[3] * inv);
  *(float4*)&o[4]   = make_float4(e[4] * inv, e[5] * inv, e[6] * inv, e[7] * inv);
  *(float4*)&o[512] = make_float4(e[8] * inv, e[9] * inv, e[10] * inv, e[11] * inv);
  *(float4*)&o[516] = make_float4(e[12] * inv, e[13] * inv, e[14] * inv, e[15] * inv);
}

// ---------------- fallback kernels (r3 mid path + f32 low path) ------------
template<bool F16>
__global__ __launch_bounds__(256) void cost_k(const float* __restrict__ audio,
                                              const float* __restrict__ video,
                                              const float* __restrict__ inv_na,
                                              const float* __restrict__ inv_nv,
                                              const float* __restrict__ lam_t,
                                              float* __restrict__ Kb,
                                              _Float16* __restrict__ Kh) {
  __shared__ _Float16 As[BM * LDH];
  __shared__ _Float16 Bs[BN * LDH];
  int b  = blockIdx.z;
  int a0 = blockIdx.x * BM;
  int j0 = blockIdx.y * BN;
  int tid  = threadIdx.x;
  int lane = tid & 63;
  int wid  = tid >> 6;
  int wm = wid >> 1, wn = wid & 1;
  const float* Ab = audio + (size_t)b * TA * DD;
  const float* Vb = video + (size_t)b * TV * DD;
  f32x4 acc[4][4];
  #pragma unroll
  for (int i = 0; i < 4; i++)
    #pragma unroll
    for (int j = 0; j < 4; j++)
      #pragma unroll
      for (int r = 0; r < 4; r++) acc[i][j][r] = 0.f;
  int frow = tid >> 4;
  int fcol = (tid & 15) * 4;
  int l16 = lane & 15, lq = lane >> 4;
  for (int kb = 0; kb < DD; kb += BK) {
    __syncthreads();
    #pragma unroll
    for (int s = 0; s < 8; s++) {
      int r = frow + s * 16;
      float4 v = *(const float4*)&Ab[(size_t)(a0 + r) * DD + kb + fcol];
      float sc = inv_na[b * TA + a0 + r];
      half4 h = { (_Float16)(v.x * sc), (_Float16)(v.y * sc),
                  (_Float16)(v.z * sc), (_Float16)(v.w * sc) };
      *(half4*)&As[r * LDH + fcol] = h;
    }
    #pragma unroll
    for (int s = 0; s < 8; s++) {
      int r = frow + s * 16;
      float4 v = *(const float4*)&Vb[(size_t)(j0 + r) * DD + kb + fcol];
      float sc = inv_nv[b * TV + j0 + r];
      half4 h = { (_Float16)(v.x * sc), (_Float16)(v.y * sc),
                  (_Float16)(v.z * sc), (_Float16)(v.w * sc) };
      *(half4*)&Bs[r * LDH + fcol] = h;
    }
    __syncthreads();
    #pragma unroll
    for (int ks = 0; ks < 2; ks++) {
      half8 af[4], bf[4];
      #pragma unroll
      for (int mf = 0; mf < 4; mf++)
        af[mf] = *(const half8*)&As[(wm * 64 + mf * 16 + l16) * LDH + ks * 32 + lq * 8];
      #pragma unroll
      for (int nf = 0; nf < 4; nf++)
        bf[nf] = *(const half8*)&Bs[(wn * 64 + nf * 16 + l16) * LDH + ks * 32 + lq * 8];
      #pragma unroll
      for (int mf = 0; mf < 4; mf++)
        #pragma unroll
        for (int nf = 0; nf < 4; nf++)
          acc[mf][nf] = __builtin_amdgcn_mfma_f32_16x16x32_f16(af[mf], bf[nf], acc[mf][nf], 0, 0, 0);
    }
  }
  float lt = *lam_t;
  float c1 = LOG2E / EPSI;
  #pragma unroll
  for (int mf = 0; mf < 4; mf++)
    #pragma unroll
    for (int nf = 0; nf < 4; nf++)
      #pragma unroll
      for (int r = 0; r < 4; r++) {
        int a = a0 + wm * 64 + mf * 16 + lq * 4 + r;
        int j = j0 + wn * 64 + nf * 16 + l16;
        float sim = acc[mf][nf][r];
        float td = fabsf((float)a * (1.0f / TA) - (float)j * (1.0f / TV));
        float val = c1 * (sim - 1.0f - lt * td);
        size_t o = ((size_t)b * TA + a) * TV + j;
        if constexpr (F16) Kh[o] = (_Float16)val;
        else               Kb[o] = val;
      }
}

__global__ __launch_bounds__(512) void iter32_k(const float* __restrict__ Kb,
                                                const float* __restrict__ Vp,
                                                float* __restrict__ pc) {
  __shared__ float lc[8][1024];
  int tid = threadIdx.x, lane = tid & 63, wid = tid >> 6;
  int row0 = (blockIdx.x * 8 + wid) * 8;
  int b = row0 >> 11;
  const float* vp = Vp + b * TV;
  float vpl[16];
  #pragma unroll
  for (int q = 0; q < 4; q++)
    *(float4*)&vpl[q * 4] = *(const float4*)&vp[q * 256 + lane * 4];
  float C[16];
  #pragma unroll
  for (int i = 0; i < 16; i++) C[i] = 0.f;
  #pragma unroll 2
  for (int r = 0; r < 8; r++) {
    const float* row = Kb + (size_t)(row0 + r) * TV;
    float e[16];
    float s = 0.f;
    #pragma unroll
    for (int q = 0; q < 4; q++) {
      float4 kv = *(const float4*)&row[q * 256 + lane * 4];
      e[q*4+0] = exp2f(kv.x + vpl[q*4+0]);
      e[q*4+1] = exp2f(kv.y + vpl[q*4+1]);
      e[q*4+2] = exp2f(kv.z + vpl[q*4+2]);
      e[q*4+3] = exp2f(kv.w + vpl[q*4+3]);
      s += e[q*4+0] + e[q*4+1] + e[q*4+2] + e[q*4+3];
    }
    s = wave_sum(s);
    float w = 1.0f / s;
    #pragma unroll
    for (int i = 0; i < 16; i++) C[i] = fmaf(e[i], w, C[i]);
  }
  #pragma unroll
  for (int q = 0; q < 4; q++)
    *(float4*)&lc[wid][q * 256 + lane * 4] =
        make_float4(C[q*4+0], C[q*4+1], C[q*4+2], C[q*4+3]);
  __syncthreads();
  #pragma unroll
  for (int k = 0; k < 2; k++) {
    int col = tid + k * 512;
    float S = 0.f;
    #pragma unroll
    for (int w = 0; w < 8; w++) S += lc[w][col];
    pc[(size_t)blockIdx.x * 1024 + col] = S;
  }
}

__global__ __launch_bounds__(256) void final32_k(float* __restrict__ Kb,
                                                 const float* __restrict__ Vp) {
  int gw   = (blockIdx.x * blockDim.x + threadIdx.x) >> 6;
  int lane = threadIdx.x & 63;
  int b = gw >> 11;
  const float* vp = Vp + b * TV;
  float* row = Kb + (size_t)gw * TV;
  float e[16];
  float s = 0.f;
  #pragma unroll
  for (int q = 0; q < 4; q++) {
    float4 kv = *(const float4*)&row[q * 256 + lane * 4];
    float4 vv = *(const float4*)&vp[q * 256 + lane * 4];
    e[q*4+0] = exp2f(kv.x + vv.x); e[q*4+1] = exp2f(kv.y + vv.y);
    e[q*4+2] = exp2f(kv.z + vv.z); e[q*4+3] = exp2f(kv.w + vv.w);
    s += e[q*4+0] + e[q*4+1] + e[q*4+2] + e[q*4+3];
  }
  s = wave_sum(s);
  float inv = 1.0f / s;
  #pragma unroll
  for (int q = 0; q < 4; q++)
    *(float4*)&row[q * 256 + lane * 4] =
        make_float4(e[q*4+0] * inv, e[q*4+1] * inv, e[q*4+2] * inv, e[q*4+3] * inv);
}

extern "C" void kernel_launch(void* const* d_in, const int* in_sizes, int n_in,
                              void* d_out, int out_size, void* d_ws, size_t ws_size,
                              hipStream_t stream) {
  const float* audio   = (const float*)d_in[0];
  const float* video   = (const float*)d_in[1];
  const float* quality = (const float*)d_in[2];
  const float* lam_t   = (const float*)d_in[3];
  const float* lam_q   = (const float*)d_in[4];

  float* out = (float*)d_out;
  float* ws  = (float*)d_ws;
  // full-path layout (f32 units)
  float* VpX    = ws + 49152;                      // 16384
  float* pc     = ws + 81920;                      // 524288 (512*1024)
  _Float16* af16 = (_Float16*)(ws + 606208);       // 32 MiB
  _Float16* vf16 = (_Float16*)(ws + 8994816);      // 16 MiB
  _Float16* KhF  = (_Float16*)(ws + 13189120);     // 64 MiB
  size_t need_full = 29966336ull * 4;

  // mid-path layout
  float* inv_na = ws;
  float* inv_nv = ws + 32768;
  float* VpM    = ws + 49152;
  float* pcM    = ws + 65536;
  _Float16* KhM = (_Float16*)(ws + 589824);
  size_t need_mid = (589824ull + 16777216ull) * 4;

  if (ws_size >= need_full) {
    norms2_k<<<12288, 256, 0, stream>>>(audio, video, af16, vf16);
    vinit_k<<<64, 256, 0, stream>>>(quality, lam_q, VpX);
    cost2_k<<<2048, 256, 0, stream>>>(af16, vf16, lam_t, KhF);
    for (int it = 0; it < NIT; it++) {
      iter16_k<<<512, 512, 0, stream>>>(KhF, VpX, pc);
      vcomb_k<<<64, 256, 0, stream>>>(pc, VpX);
    }
    final16_k<<<8192, 256, 0, stream>>>(KhF, VpX, out);
  } else if (ws_size >= need_mid) {
    norms_k<<<12288, 256, 0, stream>>>(audio, video, inv_na, inv_nv);
    vinit_k<<<64, 256, 0, stream>>>(quality, lam_q, VpM);
    cost_k<true><<<dim3(16, 8, 16), 256, 0, stream>>>(audio, video, inv_na, inv_nv,
                                                      lam_t, nullptr, KhM);
    for (int it = 0; it < NIT; it++) {
      iter16_k<<<512, 512, 0, stream>>>(KhM, VpM, pcM);
      vcomb_k<<<64, 256, 0, stream>>>(pcM, VpM);
    }
    final16_k<<<8192, 256, 0, stream>>>(KhM, VpM, out);
  } else {
    norms_k<<<12288, 256, 0, stream>>>(audio, video, inv_na, inv_nv);
    vinit_k<<<64, 256, 0, stream>>>(quality, lam_q, VpM);
    float* Kb = out;
    cost_k<false><<<dim3(16, 8, 16), 256, 0, stream>>>(audio, video, inv_na, inv_nv,
                                                       lam_t, Kb, nullptr);
    for (int it = 0; it < NIT; it++) {
      iter32_k<<<512, 512, 0, stream>>>(Kb, VpM, pcM);
      vcomb_k<<<64, 256, 0, stream>>>(pcM, VpM);
    }
    final32_k<<<8192, 256, 0, stream>>>(Kb, VpM);
  }
}